// Round 8
// baseline (234.284 us; speedup 1.0000x reference)
//
#include <hip/hip_runtime.h>
#include <hip/hip_bf16.h>

#define TA_B 2
#define TA_H 16
#define TA_S 2048
#define TA_D 64
#define KTILE 64
#define QB 128
#define BLOCK 512
#define NKT (TA_S / KTILE)

typedef __attribute__((ext_vector_type(4))) float f32x4;
typedef __attribute__((ext_vector_type(8))) short bf16x8;
typedef __attribute__((ext_vector_type(8))) unsigned short u16x8;
typedef __attribute__((ext_vector_type(4))) unsigned short u16x4;

union BF8 { u16x8 u; bf16x8 s; };

__device__ __forceinline__ unsigned short f2bf(float f) {
    union { float f; unsigned int i; } v; v.f = f;
    unsigned int x = v.i;
    unsigned int r = x + 0x7FFFu + ((x >> 16) & 1u);
    return (unsigned short)(r >> 16);
}
__device__ __forceinline__ float bf2f(unsigned short u) {
    union { unsigned int i; float f; } v; v.i = ((unsigned int)u) << 16; return v.f;
}
__device__ __forceinline__ float fexp2(float x) {
#if __has_builtin(__builtin_amdgcn_exp2f)
    return __builtin_amdgcn_exp2f(x);
#else
    return exp2f(x);
#endif
}

// Raw barrier: waits LDS ops only; global prefetch loads stay in flight
// (hipcc's __syncthreads() would drain vmcnt(0) and kill the pipeline).
__device__ __forceinline__ void barrier_lds() {
    asm volatile("s_waitcnt lgkmcnt(0)" ::: "memory");
    __builtin_amdgcn_sched_barrier(0);
    __builtin_amdgcn_s_barrier();
    __builtin_amdgcn_sched_barrier(0);
}

// ---- mask bit-pack: 33.6 MB int32 -> 1 MB bits, via wave ballot ----
__global__ __launch_bounds__(256) void pack_mask(const int* __restrict__ M,
                                                 unsigned long long* __restrict__ Mp) {
    const int nw = TA_B * TA_S * NKT;                    // 131072 words
    const int wavesTotal = (gridDim.x * blockDim.x) >> 6;
    const int wid  = (blockIdx.x * blockDim.x + threadIdx.x) >> 6;
    const int lane = threadIdx.x & 63;
    for (int w = wid; w < nw; w += wavesTotal) {
        int mv = M[(long)w * 64 + lane];
        unsigned long long bits = __ballot(mv != 0);
        if (lane == 0) Mp[w] = bits;
    }
}

// ---- prep: Kp = bf16(K+T) and Vc = bf16(V), both [bh][k][d] row-major ----
__global__ __launch_bounds__(256) void prep_kv(const float* __restrict__ K,
                                               const float* __restrict__ T,
                                               const float* __restrict__ V,
                                               unsigned short* __restrict__ Kpc,
                                               unsigned short* __restrict__ Vcb) {
    const long idx = (long)(blockIdx.x * 256 + threadIdx.x) * 8;   // 4,194,304 elems total
    f32x4 ka = *(const f32x4*)(K + idx);
    f32x4 kb = *(const f32x4*)(K + idx + 4);
    f32x4 ta = *(const f32x4*)(T + idx);
    f32x4 tb = *(const f32x4*)(T + idx + 4);
    f32x4 va = *(const f32x4*)(V + idx);
    f32x4 vb = *(const f32x4*)(V + idx + 4);
    u16x8 kp, vc;
#pragma unroll
    for (int i = 0; i < 4; ++i) {
        kp[i]     = f2bf(ka[i] + ta[i]);
        kp[i + 4] = f2bf(kb[i] + tb[i]);
        vc[i]     = f2bf(va[i]);
        vc[i + 4] = f2bf(vb[i]);
    }
    __builtin_nontemporal_store(kp, (u16x8*)(Kpc + idx));
    __builtin_nontemporal_store(vc, (u16x8*)(Vcb + idx));
}

template <bool PACKED, bool CACHED>
__global__ __launch_bounds__(BLOCK, 4) void ta_fused(
    const float* __restrict__ Qg,
    const float* __restrict__ Kg,
    const float* __restrict__ Vg,
    const float* __restrict__ Tg,
    const int* __restrict__ Mg,
    const unsigned long long* __restrict__ Mp,
    const unsigned short* __restrict__ Kpc,
    const unsigned short* __restrict__ Vcb,
    float* __restrict__ Og,
    float* __restrict__ Pg)
{
    __shared__ unsigned short sKp[KTILE][72];   // bf16(K+T): [k][d]
    __shared__ unsigned short sVt[TA_D][72];    // bf16 V^T:  [d][k^(d&56)]
    __shared__ unsigned short sP[QB][72];       // bf16 normalized p, wave-local rows,
                                                // column-swizzled: phys = col ^ ((row&3)<<4)

    const int tid  = threadIdx.x;
    const int wave = tid >> 6;                  // 0..7
    const int lane = tid & 63;
    const int c    = lane & 15;
    const int g    = lane >> 4;
    const int row0 = tid >> 3;                  // staging row 0..63
    const int cg   = (tid & 7) * 8;             // staging d-chunk

    // Bijective XCD swizzle (512 blocks): XCD x owns wids [x*64, x*64+64).
    const int did = blockIdx.x + 16 * (blockIdx.y + 16 * blockIdx.z);
    const int wid = (did & 7) * 64 + (did >> 3);
    const int q0  = (wid & 15) * QB;
    const int h   = (wid >> 4) & 15;
    const int b   = wid >> 8;

    const long bh    = (long)b * TA_H + h;
    const long xBase = bh * (long)TA_S * TA_D;
    const long pBase = bh * (long)TA_S * TA_S;
    const long mBase = (long)b * (long)TA_S * TA_S;
    const int  wq0   = wave * 16;

    // Q fragments, (1/8)*log2(e) folded -> MFMA gives s*log2e, exp2 gives exp(s).
    const float QSCALE = 0.125f * 1.4426950408889634f;
    bf16x8 qf0, qf1;
    {
        const float* qp = Qg + xBase + (long)(q0 + wq0 + c) * TA_D + g * 8;
        f32x4 a0 = *(const f32x4*)(qp);
        f32x4 a1 = *(const f32x4*)(qp + 4);
        f32x4 b0 = *(const f32x4*)(qp + 32);
        f32x4 b1 = *(const f32x4*)(qp + 36);
        BF8 u0, u1;
#pragma unroll
        for (int i = 0; i < 4; ++i) {
            u0.u[i]     = f2bf(a0[i] * QSCALE);
            u0.u[i + 4] = f2bf(a1[i] * QSCALE);
            u1.u[i]     = f2bf(b0[i] * QSCALE);
            u1.u[i + 4] = f2bf(b1[i] * QSCALE);
        }
        qf0 = u0.s; qf1 = u1.s;
    }

    // Staging registers (prefetch depth 1)
    f32x4 kA0, kA1, tA0, tA1, vA0, vA1;   // uncached tier
    u16x8 kp8, vv8;                       // cached tier

    auto loadKT = [&](int kt) {
        const long o0 = xBase + (long)(kt * KTILE + row0) * TA_D + cg;
        if constexpr (CACHED) {
            kp8 = *(const u16x8*)(Kpc + o0);
        } else {
            kA0 = *(const f32x4*)(Kg + o0); kA1 = *(const f32x4*)(Kg + o0 + 4);
            tA0 = *(const f32x4*)(Tg + o0); tA1 = *(const f32x4*)(Tg + o0 + 4);
        }
    };
    auto loadV = [&](int kt) {
        const long o0 = xBase + (long)(kt * KTILE + row0) * TA_D + cg;
        if constexpr (CACHED) {
            vv8 = *(const u16x8*)(Vcb + o0);
        } else {
            vA0 = *(const f32x4*)(Vg + o0); vA1 = *(const f32x4*)(Vg + o0 + 4);
        }
    };
    auto storeKp = [&]() {
        if constexpr (CACHED) {
            *(u16x8*)&sKp[row0][cg] = kp8;
        } else {
            u16x8 r0;
#pragma unroll
            for (int i = 0; i < 4; ++i) {
                r0[i]     = f2bf(kA0[i] + tA0[i]);
                r0[i + 4] = f2bf(kA1[i] + tA1[i]);
            }
            *(u16x8*)&sKp[row0][cg] = r0;
        }
    };
    auto storeVt = [&]() {
        const int kp = row0 ^ cg;               // XOR-chunk swizzle kills 16-way conflict
        if constexpr (CACHED) {
#pragma unroll
            for (int i = 0; i < 4; ++i) {
                sVt[cg + i][kp]     = vv8[i];
                sVt[cg + i + 4][kp] = vv8[i + 4];
            }
        } else {
#pragma unroll
            for (int i = 0; i < 4; ++i) {
                sVt[cg + i][kp]     = f2bf(vA0[i]);
                sVt[cg + i + 4][kp] = f2bf(vA1[i]);
            }
        }
    };

    // Per-(r) mask predicate: 4 floats (1.0/0.0), one per ct.
    auto maskBits = [&](int kt, int r, float* mb) {
        const int mq = q0 + wq0 + g * 4 + r;
        if constexpr (PACKED) {
            const unsigned long long w = Mp[((long)b * TA_S + mq) * NKT + kt];
            const unsigned lo = (unsigned)w, hi = (unsigned)(w >> 32);
            mb[0] = ((lo >> c) & 1u)        ? 1.0f : 0.0f;
            mb[1] = ((lo >> (16 + c)) & 1u) ? 1.0f : 0.0f;
            mb[2] = ((hi >> c) & 1u)        ? 1.0f : 0.0f;
            mb[3] = ((hi >> (16 + c)) & 1u) ? 1.0f : 0.0f;
        } else {
            const int* mp = Mg + mBase + (long)mq * TA_S + kt * KTILE;
#pragma unroll
            for (int ct = 0; ct < 4; ++ct) mb[ct] = mp[ct * 16 + c] ? 1.0f : 0.0f;
        }
    };

    // ---------------- Pass A: l[row] = sum_k mask*exp(s) ----------------
    float lpart[4] = {0.0f, 0.0f, 0.0f, 0.0f};
    loadKT(0);
    for (int kt = 0; kt < NKT; ++kt) {
        storeKp();
        loadKT(kt + 1 < NKT ? kt + 1 : 0);   // prefetch stays in flight across raw barrier
        barrier_lds();

        f32x4 acc[4];
#pragma unroll
        for (int ct = 0; ct < 4; ++ct)
#pragma unroll
            for (int j = 0; j < 4; ++j) acc[ct][j] = 0.0f;

        __builtin_amdgcn_s_setprio(1);
#pragma unroll
        for (int kk = 0; kk < 2; ++kk) {
            bf16x8 qa = kk ? qf1 : qf0;
#pragma unroll
            for (int ct = 0; ct < 4; ++ct) {
                BF8 bf; bf.u = *(const u16x8*)&sKp[ct * 16 + c][kk * 32 + g * 8];
                acc[ct] = __builtin_amdgcn_mfma_f32_16x16x32_bf16(qa, bf.s, acc[ct], 0, 0, 0);
            }
        }
        __builtin_amdgcn_s_setprio(0);

#pragma unroll
        for (int r = 0; r < 4; ++r) {
            float mb[4];
            maskBits(kt, r, mb);
#pragma unroll
            for (int ct = 0; ct < 4; ++ct)
                lpart[r] += mb[ct] * fexp2(acc[ct][r]);
        }
        barrier_lds();
    }

    loadV(0);   // KT(0) already resident from the wrap-around prefetch

    float invl[4];
#pragma unroll
    for (int r = 0; r < 4; ++r) {
        float l = lpart[r];
#pragma unroll
        for (int off = 1; off < 16; off <<= 1)
            l += __shfl_xor(l, off);
        invl[r] = (l > 0.0f) ? (1.0f / l) : 0.0f;   // all-masked row -> zeros (within threshold)
    }

    f32x4 oacc[4];
#pragma unroll
    for (int dt = 0; dt < 4; ++dt)
#pragma unroll
        for (int j = 0; j < 4; ++j) oacc[dt][j] = 0.0f;

    // ---------------- Pass B: recompute S, p=e*invl (bf16), O += p*V, stream p out ----------------
    for (int kt = 0; kt < NKT; ++kt) {
        storeKp();
        storeVt();
        const int ktn = kt + 1 < NKT ? kt + 1 : 0;
        loadKT(ktn);
        loadV(ktn);
        barrier_lds();

        f32x4 acc[4];
#pragma unroll
        for (int ct = 0; ct < 4; ++ct)
#pragma unroll
            for (int j = 0; j < 4; ++j) acc[ct][j] = 0.0f;

        __builtin_amdgcn_s_setprio(1);
#pragma unroll
        for (int kk = 0; kk < 2; ++kk) {
            bf16x8 qa = kk ? qf1 : qf0;
#pragma unroll
            for (int ct = 0; ct < 4; ++ct) {
                BF8 bf; bf.u = *(const u16x8*)&sKp[ct * 16 + c][kk * 32 + g * 8];
                acc[ct] = __builtin_amdgcn_mfma_f32_16x16x32_bf16(qa, bf.s, acc[ct], 0, 0, 0);
            }
        }
        __builtin_amdgcn_s_setprio(0);

        // normalized p -> sP (bf16, column-swizzled phys = col ^ ((row&3)<<4))
#pragma unroll
        for (int r = 0; r < 4; ++r) {
            float mb[4];
            maskBits(kt, r, mb);
#pragma unroll
            for (int ct = 0; ct < 4; ++ct) {
                float e = mb[ct] * fexp2(acc[ct][r]);
                sP[wq0 + g * 4 + r][((ct ^ r) << 4) + c] = f2bf(e * invl[r]);
            }
        }

        // PV: A = normalized p (own wave rows, de-swizzled read), B = swizzled V^T
        BF8 pa0, pa1;
        {
            const int m = c & 3;
            pa0.u = *(const u16x8*)&sP[wq0 + c][(((g >> 1) ^ m) << 4) + ((g & 1) << 3)];
            pa1.u = *(const u16x8*)&sP[wq0 + c][(((2 | (g >> 1)) ^ m) << 4) + ((g & 1) << 3)];
        }
        __builtin_amdgcn_s_setprio(1);
#pragma unroll
        for (int dt = 0; dt < 4; ++dt) {
            const int dRow = dt * 16 + c;
            const int kc0 = (g * 8) ^ (dRow & 56);
            const int kc1 = (32 + g * 8) ^ (dRow & 56);
            BF8 bv0, bv1;
            bv0.u = *(const u16x8*)&sVt[dRow][kc0];
            oacc[dt] = __builtin_amdgcn_mfma_f32_16x16x32_bf16(pa0.s, bv0.s, oacc[dt], 0, 0, 0);
            bv1.u = *(const u16x8*)&sVt[dRow][kc1];
            oacc[dt] = __builtin_amdgcn_mfma_f32_16x16x32_bf16(pa1.s, bv1.s, oacc[dt], 0, 0, 0);
        }
        __builtin_amdgcn_s_setprio(0);

        // P global store: full 128B lines per instruction.
#pragma unroll
        for (int j = 0; j < 4; ++j) {
            const int prow = 4 * j + (g & 3);        // g = lane>>4 in 0..3
            const int L0   = c * 4;                  // logical col 0..60
            const int phys = (L0 & 12) + ((((L0 >> 4) ^ (prow & 3)) << 4));
            u16x4 pv = *(const u16x4*)&sP[wq0 + prow][phys];
            f32x4 v;
#pragma unroll
            for (int i = 0; i < 4; ++i) v[i] = bf2f(pv[i]);
            __builtin_nontemporal_store(
                v, (f32x4*)(Pg + pBase + (long)(q0 + wq0 + prow) * TA_S + kt * KTILE + L0));
        }

        barrier_lds();
    }

    // O = oacc (p already normalized)
#pragma unroll
    for (int dt = 0; dt < 4; ++dt) {
#pragma unroll
        for (int r = 0; r < 4; ++r) {
            __builtin_nontemporal_store(
                oacc[dt][r],
                &Og[xBase + (long)(q0 + wq0 + g * 4 + r) * TA_D + dt * 16 + c]);
        }
    }
}

extern "C" void kernel_launch(void* const* d_in, const int* in_sizes, int n_in,
                              void* d_out, int out_size, void* d_ws, size_t ws_size,
                              hipStream_t stream) {
    const float* Q = (const float*)d_in[0];
    const float* K = (const float*)d_in[1];
    const float* V = (const float*)d_in[2];
    const float* T = (const float*)d_in[3];
    const int*   M = (const int*)d_in[4];

    float* O = (float*)d_out;
    float* P = O + (long)TA_B * TA_H * TA_S * TA_D;

    const long nElem  = (long)TA_B * TA_H * TA_S * TA_D;          // 4,194,304
    const size_t maskWs = (size_t)TA_B * TA_S * NKT * 8;          // 1 MB
    const size_t kpWs   = (size_t)nElem * 2;                      // 8 MB
    const size_t vWs    = (size_t)nElem * 2;                      // 8 MB

    unsigned long long* Mp = (unsigned long long*)d_ws;
    unsigned short* Kpc = (unsigned short*)((char*)d_ws + maskWs);
    unsigned short* Vcb = (unsigned short*)((char*)d_ws + maskWs + kpWs);

    dim3 grid(TA_S / QB, TA_H, TA_B);   // 16 x 16 x 2 = 512 blocks
    dim3 block(BLOCK);

    if (ws_size >= maskWs + kpWs + vWs) {
        hipLaunchKernelGGL(pack_mask, dim3(512), dim3(256), 0, stream, M, Mp);
        hipLaunchKernelGGL(prep_kv, dim3((unsigned)(nElem / 8 / 256)), dim3(256), 0, stream,
                           K, T, V, Kpc, Vcb);
        hipLaunchKernelGGL((ta_fused<true, true>), grid, block, 0, stream,
                           Q, K, V, T, M, Mp, Kpc, Vcb, O, P);
    } else if (ws_size >= maskWs) {
        hipLaunchKernelGGL(pack_mask, dim3(512), dim3(256), 0, stream, M, Mp);
        hipLaunchKernelGGL((ta_fused<true, false>), grid, block, 0, stream,
                           Q, K, V, T, M, Mp, Kpc, Vcb, O, P);
    } else {
        hipLaunchKernelGGL((ta_fused<false, false>), grid, block, 0, stream,
                           Q, K, V, T, M, Mp, Kpc, Vcb, O, P);
    }
}

// Round 9
// 193.278 us; speedup vs baseline: 1.2122x; 1.2122x over previous
//
#include <hip/hip_runtime.h>
#include <hip/hip_bf16.h>

#define TA_B 2
#define TA_H 16
#define TA_S 2048
#define TA_D 64
#define KTILE 64
#define QB 128
#define BLOCK 512
#define NKT (TA_S / KTILE)

typedef __attribute__((ext_vector_type(4))) float f32x4;
typedef __attribute__((ext_vector_type(8))) short bf16x8;
typedef __attribute__((ext_vector_type(8))) unsigned short u16x8;
typedef __attribute__((ext_vector_type(4))) unsigned short u16x4;

union BF8 { u16x8 u; bf16x8 s; };

__device__ __forceinline__ unsigned short f2bf(float f) {
    union { float f; unsigned int i; } v; v.f = f;
    unsigned int x = v.i;
    unsigned int r = x + 0x7FFFu + ((x >> 16) & 1u);
    return (unsigned short)(r >> 16);
}
__device__ __forceinline__ float bf2f(unsigned short u) {
    union { unsigned int i; float f; } v; v.i = ((unsigned int)u) << 16; return v.f;
}

// Raw barrier: waits LDS ops only; global prefetch loads stay in flight
// (hipcc's __syncthreads() would drain vmcnt(0) and kill the pipeline).
__device__ __forceinline__ void barrier_lds() {
    asm volatile("s_waitcnt lgkmcnt(0)" ::: "memory");
    __builtin_amdgcn_sched_barrier(0);
    __builtin_amdgcn_s_barrier();
    __builtin_amdgcn_sched_barrier(0);
}

// ---- mask bit-pack: 33.6 MB int32 -> 1 MB bits, via wave ballot ----
__global__ __launch_bounds__(256) void pack_mask(const int* __restrict__ M,
                                                 unsigned long long* __restrict__ Mp) {
    const int nw = TA_B * TA_S * NKT;                    // 131072 words
    const int wavesTotal = (gridDim.x * blockDim.x) >> 6;
    const int wid  = (blockIdx.x * blockDim.x + threadIdx.x) >> 6;
    const int lane = threadIdx.x & 63;
    for (int w = wid; w < nw; w += wavesTotal) {
        int mv = M[(long)w * 64 + lane];
        unsigned long long bits = __ballot(mv != 0);
        if (lane == 0) Mp[w] = bits;
    }
}

template <bool PACKED>
__global__ __launch_bounds__(BLOCK, 4) void ta_fused(
    const float* __restrict__ Qg,
    const float* __restrict__ Kg,
    const float* __restrict__ Vg,
    const float* __restrict__ Tg,
    const int* __restrict__ Mg,
    const unsigned long long* __restrict__ Mp,
    float* __restrict__ Og,
    float* __restrict__ Pg)
{
    // Double-buffered staging (parity = kt&1): one barrier per tile.
    __shared__ unsigned short sKp[2][KTILE][72];   // bf16(K+T): [k][d]
    __shared__ unsigned short sVt[2][TA_D][72];    // bf16 V^T:  [d][k^(d&56)]
    __shared__ unsigned short sP[QB][72];          // bf16 normalized p, wave-private rows,
                                                   // column-swizzled: phys = col ^ ((row&3)<<4)

    const int tid  = threadIdx.x;
    const int wave = tid >> 6;                  // 0..7
    const int lane = tid & 63;
    const int c    = lane & 15;
    const int g    = lane >> 4;
    const int row0 = tid >> 3;                  // staging row 0..63
    const int cg   = (tid & 7) * 8;             // staging d-chunk

    // Bijective XCD swizzle (512 blocks): XCD x owns wids [x*64, x*64+64).
    const int did = blockIdx.x + 16 * (blockIdx.y + 16 * blockIdx.z);
    const int wid = (did & 7) * 64 + (did >> 3);
    const int q0  = (wid & 15) * QB;
    const int h   = (wid >> 4) & 15;
    const int b   = wid >> 8;

    const long bh    = (long)b * TA_H + h;
    const long xBase = bh * (long)TA_S * TA_D;
    const long pBase = bh * (long)TA_S * TA_S;
    const long mBase = (long)b * (long)TA_S * TA_S;
    const int  wq0   = wave * 16;

    // Q fragments, 1/sqrt(64) folded (exact pow2). Lane (c,g): Q[m=c][k=g*8+i], +32.
    bf16x8 qf0, qf1;
    {
        const float* qp = Qg + xBase + (long)(q0 + wq0 + c) * TA_D + g * 8;
        f32x4 a0 = *(const f32x4*)(qp);
        f32x4 a1 = *(const f32x4*)(qp + 4);
        f32x4 b0 = *(const f32x4*)(qp + 32);
        f32x4 b1 = *(const f32x4*)(qp + 36);
        BF8 u0, u1;
#pragma unroll
        for (int i = 0; i < 4; ++i) {
            u0.u[i]     = f2bf(a0[i] * 0.125f);
            u0.u[i + 4] = f2bf(a1[i] * 0.125f);
            u1.u[i]     = f2bf(b0[i] * 0.125f);
            u1.u[i + 4] = f2bf(b1[i] * 0.125f);
        }
        qf0 = u0.s; qf1 = u1.s;
    }

    // Staging registers (prefetch depth 1)
    f32x4 kA0, kA1, tA0, tA1, vA0, vA1;

    auto loadKT = [&](int kt) {
        const long o0 = xBase + (long)(kt * KTILE + row0) * TA_D + cg;
        kA0 = *(const f32x4*)(Kg + o0); kA1 = *(const f32x4*)(Kg + o0 + 4);
        tA0 = *(const f32x4*)(Tg + o0); tA1 = *(const f32x4*)(Tg + o0 + 4);
    };
    auto loadV = [&](int kt) {
        const long o0 = xBase + (long)(kt * KTILE + row0) * TA_D + cg;
        vA0 = *(const f32x4*)(Vg + o0); vA1 = *(const f32x4*)(Vg + o0 + 4);
    };
    auto storeKp = [&](int p) {
        u16x8 r0;
#pragma unroll
        for (int i = 0; i < 4; ++i) {
            r0[i]     = f2bf(kA0[i] + tA0[i]);
            r0[i + 4] = f2bf(kA1[i] + tA1[i]);
        }
        *(u16x8*)&sKp[p][row0][cg] = r0;
    };
    auto storeVt = [&](int p) {
        const int kp = row0 ^ cg;               // XOR-chunk swizzle kills 16-way conflict
#pragma unroll
        for (int i = 0; i < 4; ++i) {
            sVt[p][cg + i][kp]     = f2bf(vA0[i]);
            sVt[p][cg + i + 4][kp] = f2bf(vA1[i]);
        }
    };

    // Per-(r) mask predicate: 4 floats (1.0/0.0), one per ct.
    auto maskBits = [&](int kt, int r, float* mb) {
        const int mq = q0 + wq0 + g * 4 + r;
        if constexpr (PACKED) {
            const unsigned long long w = Mp[((long)b * TA_S + mq) * NKT + kt];
            const unsigned lo = (unsigned)w, hi = (unsigned)(w >> 32);
            mb[0] = ((lo >> c) & 1u)        ? 1.0f : 0.0f;
            mb[1] = ((lo >> (16 + c)) & 1u) ? 1.0f : 0.0f;
            mb[2] = ((hi >> c) & 1u)        ? 1.0f : 0.0f;
            mb[3] = ((hi >> (16 + c)) & 1u) ? 1.0f : 0.0f;
        } else {
            const int* mp = Mg + mBase + (long)mq * TA_S + kt * KTILE;
#pragma unroll
            for (int ct = 0; ct < 4; ++ct) mb[ct] = mp[ct * 16 + c] ? 1.0f : 0.0f;
        }
    };

    // ---------------- Pass A: l[row] = sum_k mask*exp(s) ----------------
    float lpart[4] = {0.0f, 0.0f, 0.0f, 0.0f};
    loadKT(0);
    for (int kt = 0; kt < NKT; ++kt) {
        const int p = kt & 1;
        storeKp(p);
        loadKT(kt + 1 < NKT ? kt + 1 : 0);   // prefetch stays in flight across raw barrier
        barrier_lds();                        // staging(p) complete; laggards read p^1 safely

        f32x4 acc[4];
#pragma unroll
        for (int ct = 0; ct < 4; ++ct)
#pragma unroll
            for (int j = 0; j < 4; ++j) acc[ct][j] = 0.0f;

        __builtin_amdgcn_s_setprio(1);
#pragma unroll
        for (int kk = 0; kk < 2; ++kk) {
            bf16x8 qa = kk ? qf1 : qf0;
#pragma unroll
            for (int ct = 0; ct < 4; ++ct) {
                BF8 bf; bf.u = *(const u16x8*)&sKp[p][ct * 16 + c][kk * 32 + g * 8];
                acc[ct] = __builtin_amdgcn_mfma_f32_16x16x32_bf16(qa, bf.s, acc[ct], 0, 0, 0);
            }
        }
        __builtin_amdgcn_s_setprio(0);

#pragma unroll
        for (int r = 0; r < 4; ++r) {
            float mb[4];
            maskBits(kt, r, mb);
#pragma unroll
            for (int ct = 0; ct < 4; ++ct)
                lpart[r] += mb[ct] * __expf(acc[ct][r]);
        }
        // no trailing barrier: next tile writes buffer p^1
    }

    loadV(0);   // KT(0) regs already resident from the wrap-around prefetch

    float invl[4];
#pragma unroll
    for (int r = 0; r < 4; ++r) {
        float l = lpart[r];
#pragma unroll
        for (int off = 1; off < 16; off <<= 1)
            l += __shfl_xor(l, off);
        invl[r] = (l > 0.0f) ? (1.0f / l) : 0.0f;   // all-masked row -> zeros (within threshold)
    }

    f32x4 oacc[4];
#pragma unroll
    for (int dt = 0; dt < 4; ++dt)
#pragma unroll
        for (int j = 0; j < 4; ++j) oacc[dt][j] = 0.0f;

    // ---------------- Pass B: recompute S, p=e*invl (bf16), O += p*V, stream p out ----------------
    // Pass A ended computing buf[31&1]=1; pass B starts writing buf0 — disjoint, no barrier needed.
    for (int kt = 0; kt < NKT; ++kt) {
        const int p = kt & 1;
        storeKp(p);
        storeVt(p);
        const int ktn = kt + 1 < NKT ? kt + 1 : 0;
        loadKT(ktn);
        loadV(ktn);
        barrier_lds();

        f32x4 acc[4];
#pragma unroll
        for (int ct = 0; ct < 4; ++ct)
#pragma unroll
            for (int j = 0; j < 4; ++j) acc[ct][j] = 0.0f;

        __builtin_amdgcn_s_setprio(1);
#pragma unroll
        for (int kk = 0; kk < 2; ++kk) {
            bf16x8 qa = kk ? qf1 : qf0;
#pragma unroll
            for (int ct = 0; ct < 4; ++ct) {
                BF8 bf; bf.u = *(const u16x8*)&sKp[p][ct * 16 + c][kk * 32 + g * 8];
                acc[ct] = __builtin_amdgcn_mfma_f32_16x16x32_bf16(qa, bf.s, acc[ct], 0, 0, 0);
            }
        }
        __builtin_amdgcn_s_setprio(0);

        // normalized p -> sP (bf16, column-swizzled phys = col ^ ((row&3)<<4)).
        // sP is wave-private (own 16 rows written/read by own wave only).
#pragma unroll
        for (int r = 0; r < 4; ++r) {
            float mb[4];
            maskBits(kt, r, mb);
#pragma unroll
            for (int ct = 0; ct < 4; ++ct) {
                float e = mb[ct] * __expf(acc[ct][r]);
                sP[wq0 + g * 4 + r][((ct ^ r) << 4) + c] = f2bf(e * invl[r]);
            }
        }

        // PV: A = normalized p (own wave rows, de-swizzled read), B = swizzled V^T
        BF8 pa0, pa1;
        {
            const int m = c & 3;
            pa0.u = *(const u16x8*)&sP[wq0 + c][(((g >> 1) ^ m) << 4) + ((g & 1) << 3)];
            pa1.u = *(const u16x8*)&sP[wq0 + c][(((2 | (g >> 1)) ^ m) << 4) + ((g & 1) << 3)];
        }
        __builtin_amdgcn_s_setprio(1);
#pragma unroll
        for (int dt = 0; dt < 4; ++dt) {
            const int dRow = dt * 16 + c;
            const int kc0 = (g * 8) ^ (dRow & 56);
            const int kc1 = (32 + g * 8) ^ (dRow & 56);
            BF8 bv0, bv1;
            bv0.u = *(const u16x8*)&sVt[p][dRow][kc0];
            oacc[dt] = __builtin_amdgcn_mfma_f32_16x16x32_bf16(pa0.s, bv0.s, oacc[dt], 0, 0, 0);
            bv1.u = *(const u16x8*)&sVt[p][dRow][kc1];
            oacc[dt] = __builtin_amdgcn_mfma_f32_16x16x32_bf16(pa1.s, bv1.s, oacc[dt], 0, 0, 0);
        }
        __builtin_amdgcn_s_setprio(0);

        // P global store: full 128B lines per instruction (reads own wave's sP rows).
#pragma unroll
        for (int j = 0; j < 4; ++j) {
            const int prow = 4 * j + (g & 3);        // g = lane>>4 in 0..3
            const int L0   = c * 4;                  // logical col 0..60
            const int phys = (L0 & 12) + ((((L0 >> 4) ^ (prow & 3)) << 4));
            u16x4 pv = *(const u16x4*)&sP[wq0 + prow][phys];
            f32x4 v;
#pragma unroll
            for (int i = 0; i < 4; ++i) v[i] = bf2f(pv[i]);
            __builtin_nontemporal_store(
                v, (f32x4*)(Pg + pBase + (long)(q0 + wq0 + prow) * TA_S + kt * KTILE + L0));
        }
        // no trailing barrier: next tile writes buffer p^1
    }

    // O = oacc (p already normalized)
#pragma unroll
    for (int dt = 0; dt < 4; ++dt) {
#pragma unroll
        for (int r = 0; r < 4; ++r) {
            __builtin_nontemporal_store(
                oacc[dt][r],
                &Og[xBase + (long)(q0 + wq0 + g * 4 + r) * TA_D + dt * 16 + c]);
        }
    }
}

extern "C" void kernel_launch(void* const* d_in, const int* in_sizes, int n_in,
                              void* d_out, int out_size, void* d_ws, size_t ws_size,
                              hipStream_t stream) {
    const float* Q = (const float*)d_in[0];
    const float* K = (const float*)d_in[1];
    const float* V = (const float*)d_in[2];
    const float* T = (const float*)d_in[3];
    const int*   M = (const int*)d_in[4];

    float* O = (float*)d_out;
    float* P = O + (long)TA_B * TA_H * TA_S * TA_D;

    unsigned long long* Mp = (unsigned long long*)d_ws;
    const size_t needWs = (size_t)TA_B * TA_S * NKT * sizeof(unsigned long long);  // 1 MB

    dim3 grid(TA_S / QB, TA_H, TA_B);   // 16 x 16 x 2 = 512 blocks
    dim3 block(BLOCK);

    if (ws_size >= needWs) {
        hipLaunchKernelGGL(pack_mask, dim3(512), dim3(256), 0, stream, M, Mp);
        hipLaunchKernelGGL(ta_fused<true>, grid, block, 0, stream, Q, K, V, T, M, Mp, O, P);
    } else {
        hipLaunchKernelGGL(ta_fused<false>, grid, block, 0, stream, Q, K, V, T, M, Mp, O, P);
    }
}